// Round 1
// baseline (621.912 us; speedup 1.0000x reference)
//
#include <hip/hip_runtime.h>
#include <math.h>

// ---------------------------------------------------------------------------
// Fused GEMV with split-K: out[b][col] = sum_i x[b][i] * W[i][col]
// x: [16][4096] (stride 4096). Three weight matrices selected by col range
// (for QKV fusion); pass n0 >= NC to use only W0 (output projection).
// Writes partials: part[seg][16][NC]. Grid: (NC/512, 32). Block: 256.
// Each thread owns 2 consecutive cols (float2 weight loads, coalesced).
// ---------------------------------------------------------------------------
__global__ __launch_bounds__(256) void gemv_part(
    const float* __restrict__ x,
    const float* __restrict__ W0, const float* __restrict__ W1,
    const float* __restrict__ W2,
    int n0, int n01, int ld0, int ld1, int ld2,
    int NC, float* __restrict__ part)
{
    __shared__ float xs[128][16];   // [i within segment][batch]
    const int tid = threadIdx.x;
    const int i0  = blockIdx.y * 128;

    // stage x segment: coalesced 128-float rows per batch, scattered LDS write
    for (int idx = tid; idx < 2048; idx += 256) {
        const int b = idx >> 7, ii = idx & 127;
        xs[ii][b] = x[b * 4096 + i0 + ii];
    }
    __syncthreads();

    const int col = blockIdx.x * 512 + tid * 2;
    const float* W; int ld, wc;
    if (col < n0)       { W = W0; ld = ld0; wc = col; }
    else if (col < n01) { W = W1; ld = ld1; wc = col - n0; }
    else                { W = W2; ld = ld2; wc = col - n01; }

    float2 acc[16];
#pragma unroll
    for (int b = 0; b < 16; ++b) acc[b] = make_float2(0.f, 0.f);

    const float* wp = W + (size_t)i0 * ld + wc;
#pragma unroll 4
    for (int ii = 0; ii < 128; ++ii) {
        const float2 wv = *(const float2*)wp; wp += ld;
        float xv[16];
        *(float4*)&xv[0]  = *(const float4*)&xs[ii][0];   // broadcast b128
        *(float4*)&xv[4]  = *(const float4*)&xs[ii][4];
        *(float4*)&xv[8]  = *(const float4*)&xs[ii][8];
        *(float4*)&xv[12] = *(const float4*)&xs[ii][12];
#pragma unroll
        for (int b = 0; b < 16; ++b) {
            acc[b].x = fmaf(xv[b], wv.x, acc[b].x);
            acc[b].y = fmaf(xv[b], wv.y, acc[b].y);
        }
    }

    float* pp = part + (size_t)blockIdx.y * 16 * NC + col;
#pragma unroll
    for (int b = 0; b < 16; ++b) *(float2*)(pp + (size_t)b * NC) = acc[b];
}

// ---------------------------------------------------------------------------
// Sum 32 split-K partials for QKV and apply RoPE to q (cols<4096) and
// k (4096..5119). Pairs are (even,odd) interleaved within each 128-dim head.
// Grid: 192x256 covers 49152 pairs of [16][6144].
// ---------------------------------------------------------------------------
__global__ __launch_bounds__(256) void reduce_rope(
    const float* __restrict__ part, const float* __restrict__ cosb,
    const float* __restrict__ sinb, float* __restrict__ xqkv)
{
    const int pidx = blockIdx.x * 256 + threadIdx.x;
    const int b    = pidx / 3072;
    const int col  = (pidx % 3072) * 2;
    float2 a = make_float2(0.f, 0.f);
#pragma unroll 4
    for (int s = 0; s < 32; ++s) {
        const float2 v = *(const float2*)(part + ((size_t)s * 16 + b) * 6144 + col);
        a.x += v.x; a.y += v.y;
    }
    if (col < 5120) {                      // q or k: rotate the pair
        const int p = (col >> 1) & 63;     // pair index within head
        const float c = cosb[p], sn = sinb[p];
        a = make_float2(a.x * c - a.y * sn, a.x * sn + a.y * c);
    }
    *(float2*)(xqkv + (size_t)b * 6144 + col) = a;
}

// ---------------------------------------------------------------------------
// Flash-style decode attention. Block = (batch, kv_head, chunk); 4 waves,
// wave w handles q head kh*4+w. K tile XOR-swizzled in LDS so that the
// lane<->position QK loop reads conflict-free float4s; V linear.
// Writes per-(b,h,chunk) partials: 128 acc + m + l (stride 132).
// ---------------------------------------------------------------------------
__global__ __launch_bounds__(256) void attn_kernel(
    const float* __restrict__ xqkv,
    const float* __restrict__ cache_k, const float* __restrict__ cache_v,
    const float* __restrict__ shk, const float* __restrict__ shv,
    const int* __restrict__ sp_ptr, const int* __restrict__ spl_ptr,
    float* __restrict__ apart)
{
    __shared__ float k_lds[64 * 128];   // swizzled
    __shared__ float v_lds[64 * 128];   // linear
    __shared__ float q_lds[512];        // 4 heads x 128
    __shared__ float p_lds[256];        // 4 waves x 64 probs

    const int bid = blockIdx.x;
    const int b = bid >> 5, r = bid & 31, kh = r >> 2, chunk = r & 3;
    const int tid = threadIdx.x, w = tid >> 6, lane = tid & 63;
    const int start_pos = *sp_ptr, spl = *spl_ptr;
    const int P = start_pos + 1;                 // total kv positions
    const int ntiles = (P + 63) >> 6;
    const int tpc = (ntiles + 3) >> 2;
    const int t0 = chunk * tpc;
    const int t1 = min(t0 + tpc, ntiles);

    // q for this block's 4 heads (contiguous 512 floats)
    for (int idx = tid; idx < 512; idx += 256)
        q_lds[idx] = xqkv[b * 6144 + kh * 512 + idx];

    float  m = -INFINITY, lsum = 0.f;
    float2 acc = make_float2(0.f, 0.f);          // lane owns dims 2l, 2l+1

    for (int t = t0; t < t1; ++t) {
        __syncthreads();                          // LDS reuse fence
        const int base = t << 6;

        // ---- stage K/V tile: 64 rows x 32 float4 quads ----
        for (int idx = tid; idx < 2048; idx += 256) {
            const int row = idx >> 5, q4 = idx & 31;
            const int pos = base + row;
            float4 kk = make_float4(0.f, 0.f, 0.f, 0.f);
            float4 vv = make_float4(0.f, 0.f, 0.f, 0.f);
            if (pos < P) {
                const float *ks, *vs;
                if (pos < spl) {                          // shared prefix
                    const size_t off = ((size_t)pos * 8 + kh) * 128;
                    ks = shk + off; vs = shv + off;
                } else if (pos < P - 1) {                 // per-batch cache
                    const size_t off = ((size_t)b * 4096 + (pos - spl)) * 1024
                                     + (size_t)kh * 128;
                    ks = cache_k + off; vs = cache_v + off;
                } else {                                  // new roped k / new v
                    ks = xqkv + b * 6144 + 4096 + kh * 128;
                    vs = xqkv + b * 6144 + 5120 + kh * 128;
                }
                kk = ((const float4*)ks)[q4];
                vv = ((const float4*)vs)[q4];
            }
            ((float4*)k_lds)[(row << 5) + (q4 ^ (row & 7))] = kk;  // swizzle
            ((float4*)v_lds)[(row << 5) + q4] = vv;
        }
        __syncthreads();

        // ---- QK^T: lane <-> position ----
        float s = 0.f;
#pragma unroll
        for (int d4 = 0; d4 < 32; ++d4) {
            const float4 kk = ((const float4*)k_lds)[(lane << 5) + (d4 ^ (lane & 7))];
            const float4 qq = ((const float4*)q_lds)[(w << 5) + d4];
            s = fmaf(kk.x, qq.x, s); s = fmaf(kk.y, qq.y, s);
            s = fmaf(kk.z, qq.z, s); s = fmaf(kk.w, qq.w, s);
        }
        s *= 0.08838834764831845f;                // 1/sqrt(128)
        if (base + lane >= P) s = -INFINITY;

        // ---- online softmax (wave reduce over 64 positions) ----
        float tmax = s;
#pragma unroll
        for (int off = 32; off; off >>= 1) tmax = fmaxf(tmax, __shfl_xor(tmax, off));
        const float mnew  = fmaxf(m, tmax);       // finite: tile has >=1 valid pos
        const float alpha = __expf(m - mnew);     // exp(-inf)=0 on first tile
        const float p     = __expf(s - mnew);
        float psum = p;
#pragma unroll
        for (int off = 32; off; off >>= 1) psum += __shfl_xor(psum, off);
        lsum = lsum * alpha + psum;
        acc.x *= alpha; acc.y *= alpha;
        m = mnew;
        p_lds[(w << 6) + lane] = p;               // same-wave: lgkmcnt ordering

        // ---- PV: lane <-> dim pair ----
#pragma unroll 8
        for (int j = 0; j < 64; ++j) {
            const float  pf = p_lds[(w << 6) + j];                 // broadcast
            const float2 vv = ((const float2*)v_lds)[(j << 6) + lane];
            acc.x = fmaf(pf, vv.x, acc.x);
            acc.y = fmaf(pf, vv.y, acc.y);
        }
    }

    float* pp = apart + (size_t)((b * 32 + kh * 4 + w) * 4 + chunk) * 132;
    ((float2*)pp)[lane] = acc;                    // dim d stored at pp[d]
    if (lane == 0) { pp[128] = m; pp[129] = lsum; }
}

// ---------------------------------------------------------------------------
// Merge the 4 chunk partials per (b,h): standard m/l rescale, normalize.
// Grid: 512 blocks x 128 threads (thread = head dim).
// ---------------------------------------------------------------------------
__global__ __launch_bounds__(128) void attn_combine(
    const float* __restrict__ apart, float* __restrict__ attn_out)
{
    const int bh = blockIdx.x;
    const int d  = threadIdx.x;
    const float* p0 = apart + (size_t)bh * 4 * 132;
    float M = -INFINITY;
#pragma unroll
    for (int c = 0; c < 4; ++c) M = fmaxf(M, p0[c * 132 + 128]);
    float L = 0.f, o = 0.f;
#pragma unroll
    for (int c = 0; c < 4; ++c) {
        const float e = __expf(p0[c * 132 + 128] - M);   // empty chunk -> 0
        L += p0[c * 132 + 129] * e;
        o  = fmaf(p0[c * 132 + d], e, o);
    }
    attn_out[(size_t)bh * 128 + d] = o / L;
}

// ---------------------------------------------------------------------------
// Sum 32 split-K partials of the output projection -> d_out.
// Grid: 128x256 covers 32768 pairs of [16][4096].
// ---------------------------------------------------------------------------
__global__ __launch_bounds__(256) void reduce_sum(
    const float* __restrict__ part, float* __restrict__ out)
{
    const int pidx = blockIdx.x * 256 + threadIdx.x;
    const int b    = pidx / 2048;
    const int col  = (pidx % 2048) * 2;
    float2 a = make_float2(0.f, 0.f);
#pragma unroll 4
    for (int s = 0; s < 32; ++s) {
        const float2 v = *(const float2*)(part + ((size_t)s * 16 + b) * 4096 + col);
        a.x += v.x; a.y += v.y;
    }
    *(float2*)(out + (size_t)b * 4096 + col) = a;
}

// ---------------------------------------------------------------------------
extern "C" void kernel_launch(void* const* d_in, const int* in_sizes, int n_in,
                              void* d_out, int out_size, void* d_ws, size_t ws_size,
                              hipStream_t stream)
{
    (void)in_sizes; (void)n_in; (void)out_size; (void)ws_size;
    const float* x   = (const float*)d_in[0];
    const float* wq  = (const float*)d_in[1];
    const float* wk  = (const float*)d_in[2];
    const float* wv  = (const float*)d_in[3];
    const float* wo  = (const float*)d_in[4];
    const float* ck  = (const float*)d_in[5];
    const float* cv  = (const float*)d_in[6];
    const float* shk = (const float*)d_in[7];
    const float* shv = (const float*)d_in[8];
    const float* fc  = (const float*)d_in[9];
    const float* fs  = (const float*)d_in[10];
    const int*   sp  = (const int*)d_in[11];
    const int*   spl = (const int*)d_in[12];

    float* ws    = (float*)d_ws;
    float* part  = ws;              // 32*16*6144 = 3,145,728 f  (reused for WO)
    float* xqkv  = ws + 3145728;    //       98,304 f : roped q|k|v  [16][6144]
    float* apart = ws + 3244032;    //      270,336 f : attn partials
    float* aout  = ws + 3514368;    //       65,536 f : attn output [16][4096]
                                    // total ~13.7 MiB of d_ws

    // 1. fused QKV projection (split-K partials)
    gemv_part<<<dim3(12, 32), 256, 0, stream>>>(
        x, wq, wk, wv, 4096, 5120, 4096, 1024, 1024, 6144, part);
    // 2. reduce + RoPE -> xqkv
    reduce_rope<<<192, 256, 0, stream>>>(part, fc, fs, xqkv);
    // 3. attention over shared prefix + batch cache + new token
    attn_kernel<<<512, 256, 0, stream>>>(xqkv, ck, cv, shk, shv, sp, spl, apart);
    // 4. merge chunk partials
    attn_combine<<<512, 128, 0, stream>>>(apart, aout);
    // 5. output projection (split-K partials)
    gemv_part<<<dim3(8, 32), 256, 0, stream>>>(
        aout, wo, wo, wo, 4096, 8192, 4096, 4096, 4096, 4096, part);
    // 6. final reduce -> d_out
    reduce_sum<<<128, 256, 0, stream>>>(part, (float*)d_out);
}